// Round 2
// baseline (551.969 us; speedup 1.0000x reference)
//
#include <hip/hip_runtime.h>
#include <hip/hip_cooperative_groups.h>
#include <math.h>

namespace cg = cooperative_groups;

#define N_NODES 8192
#define F_IN 512
#define NH1 8
#define C1 8
#define D1 64   // NH1*C1
#define NC 16
#define E_EDGES 262144
#define TOT_EDGES (E_EDGES + N_NODES)
#define NEG_SLOPE 0.2f
#define CAP 128   // per-node edge cache capacity (max degree ~65 incl self-loop)

// ---- GEMM1 + fused logits1 (+ counts zeroing): h1pre[N,64] = x @ W1 ----------
// BM=32 -> 256 blocks (all CUs busy). Thread tile 2x4.
// Also zeroes counts[8192] (32 per block) so the separate memset dispatch dies;
// gemm1 fully precedes the CSR cooperative kernel in stream order.
__global__ __launch_bounds__(256) void gemm1_k(const float* __restrict__ x,
                                               const float* __restrict__ W1,
                                               const float* __restrict__ a_src1,
                                               const float* __restrict__ a_dst1,
                                               float* __restrict__ h1pre,
                                               float* __restrict__ als1,
                                               float* __restrict__ ald1,
                                               int* __restrict__ counts) {
    __shared__ __align__(16) float As[32 * 34];  // [k=32][m=32 +2 pad]
    __shared__ __align__(16) float Bs[32 * 68];  // [k=32][n=64 +4 pad]
    int tid = threadIdx.x;
    if (tid < 32) counts[blockIdx.x * 32 + tid] = 0;
    int rowBase = blockIdx.x * 32;
    int rm = tid >> 4, rn = tid & 15;            // rows rm*2.., cols rn*4..
    float acc[2][4] = {};
    for (int k0 = 0; k0 < F_IN; k0 += 32) {
#pragma unroll
        for (int j = 0; j < 4; ++j) {            // A tile: 32 rows x 32 k
            int i = tid + 256 * j;
            int r = i >> 5, c = i & 31;
            As[c * 34 + r] = x[(rowBase + r) * F_IN + k0 + c];
        }
#pragma unroll
        for (int j = 0; j < 8; ++j) {            // B tile: 32 k x 64 cols
            int i = tid + 256 * j;
            int rr = i >> 6, cc = i & 63;
            Bs[rr * 68 + cc] = W1[(k0 + rr) * D1 + cc];
        }
        __syncthreads();
#pragma unroll
        for (int kk = 0; kk < 32; ++kk) {
            float2 a = *(const float2*)&As[kk * 34 + rm * 2];
            float4 b = *(const float4*)&Bs[kk * 68 + rn * 4];
            float av[2] = {a.x, a.y};
            float bv[4] = {b.x, b.y, b.z, b.w};
#pragma unroll
            for (int jj = 0; jj < 2; ++jj)
#pragma unroll
                for (int ll = 0; ll < 4; ++ll)
                    acc[jj][ll] = fmaf(av[jj], bv[ll], acc[jj][ll]);
        }
        __syncthreads();
    }
    int h = rn >> 1, half = rn & 1;
#pragma unroll
    for (int jj = 0; jj < 2; ++jj) {
        int row = rowBase + rm * 2 + jj;
        float4 o = {acc[jj][0], acc[jj][1], acc[jj][2], acc[jj][3]};
        *(float4*)&h1pre[(size_t)row * D1 + rn * 4] = o;
        // fused logits1: partial per-head dot, pair-reduce across rn^1
        float ps = 0.f, pd = 0.f;
#pragma unroll
        for (int ll = 0; ll < 4; ++ll) {
            ps = fmaf(acc[jj][ll], a_src1[h * C1 + half * 4 + ll], ps);
            pd = fmaf(acc[jj][ll], a_dst1[h * C1 + half * 4 + ll], pd);
        }
        ps += __shfl_xor(ps, 1);
        pd += __shfl_xor(pd, 1);
        if (half == 0) {
            als1[row * NH1 + h] = ps;
            ald1[row * NH1 + h] = pd;
        }
    }
}

// ------- CSR build fused: hist -> scan -> scatter, one cooperative dispatch -------
// 256 blocks x 1024 threads = 1 block/CU, co-resident by construction.
__global__ __launch_bounds__(1024) void csr_coop_k(const int* __restrict__ ei,
                                                   int* __restrict__ counts,
                                                   int* __restrict__ offsets,
                                                   int* __restrict__ cursor,
                                                   int* __restrict__ csr) {
    __shared__ int wtot[16];
    __shared__ int wbase[16];
    cg::grid_group grid = cg::this_grid();
    int gtid = blockIdx.x * 1024 + threadIdx.x;      // 262144 threads
    // --- phase 1: histogram ---
    for (int i = gtid; i < TOT_EDGES; i += 256 * 1024) {
        int dst = (i < E_EDGES) ? ei[E_EDGES + i] : (i - E_EDGES);
        atomicAdd(&counts[dst], 1);
    }
    __threadfence();
    grid.sync();
    // --- phase 2: exclusive scan of 8192 counts (block 0 only) ---
    if (blockIdx.x == 0) {
        int t = threadIdx.x;
        int lane = t & 63, wid = t >> 6;
        int local[8];
        int s = 0;
#pragma unroll
        for (int j = 0; j < 8; ++j) { local[j] = counts[t * 8 + j]; s += local[j]; }
        int incl = s;
#pragma unroll
        for (int d = 1; d < 64; d <<= 1) {
            int v = __shfl_up(incl, d);
            if (lane >= d) incl += v;
        }
        if (lane == 63) wtot[wid] = incl;
        __syncthreads();
        if (t < 16) {
            int v = wtot[t];
            int iv = v;
#pragma unroll
            for (int d = 1; d < 16; d <<= 1) {
                int u = __shfl_up(iv, d);
                if (t >= d) iv += u;
            }
            wbase[t] = iv - v;   // exclusive
        }
        __syncthreads();
        int run = wbase[wid] + incl - s;   // exclusive prefix for this thread
#pragma unroll
        for (int j = 0; j < 8; ++j) {
            offsets[t * 8 + j] = run;
            cursor[t * 8 + j] = run;
            run += local[j];
        }
        if (t == 1023) offsets[8192] = run;
    }
    __threadfence();
    grid.sync();
    // --- phase 3: scatter ---
    for (int i = gtid; i < TOT_EDGES; i += 256 * 1024) {
        int src, dst;
        if (i < E_EDGES) { src = ei[i]; dst = ei[E_EDGES + i]; }
        else             { src = i - E_EDGES; dst = src; }
        int pos = atomicAdd(&cursor[dst], 1);
        csr[pos] = src;
    }
}

// -- Layer-1 softmax+agg, fused ELU + gemm2 + logits2; one wave per dst node --
__global__ __launch_bounds__(64) void agg1_k(const float* __restrict__ h1pre,
                                             const float* __restrict__ als1, const float* __restrict__ ald1,
                                             const int* __restrict__ offsets, const int* __restrict__ csr,
                                             const float* __restrict__ b1,
                                             const float* __restrict__ W2,
                                             const float* __restrict__ a_src2, const float* __restrict__ a_dst2,
                                             float* __restrict__ h2pre,
                                             float* __restrict__ als2, float* __restrict__ ald2) {
    __shared__ int   csr_s[CAP];
    __shared__ float vbuf[CAP * NH1];
    __shared__ float vals[64];
    int n = blockIdx.x, t = threadIdx.x;
    int beg = offsets[n], end = offsets[n + 1];
    int deg = end - beg;
    float val;
    if (deg <= CAP) {
        // preload neighbor ids with all 64 lanes (kills the csr->als1 dep chain)
        for (int i = t; i < deg; i += 64) csr_s[i] = csr[beg + i];
        __syncthreads();
        int h = t & 7, eo = t >> 3;              // 8 edges in flight x 8 heads
        float aldh = ald1[n * NH1 + h];
        float m = -3.4e38f;
        for (int e = eo; e < deg; e += 8) {
            int s = csr_s[e];
            float v = als1[s * NH1 + h] + aldh;
            v = v > 0.f ? v : NEG_SLOPE * v;
            vbuf[e * NH1 + h] = v;
            m = fmaxf(m, v);
        }
        m = fmaxf(m, __shfl_xor(m, 8));
        m = fmaxf(m, __shfl_xor(m, 16));
        m = fmaxf(m, __shfl_xor(m, 32));
        float den = 0.f;
        for (int e = eo; e < deg; e += 8) {
            float w = expf(vbuf[e * NH1 + h] - m);
            vbuf[e * NH1 + h] = w;               // cache the weight
            den += w;
        }
        den += __shfl_xor(den, 8);
        den += __shfl_xor(den, 16);
        den += __shfl_xor(den, 32);
        __syncthreads();
        // aggregation: lane t owns output column t, head q = t>>3
        int q = t >> 3;
        float dq = __shfl(den, q);
        float acc = 0.f;
        int e = 0;
        for (; e + 4 <= deg; e += 4) {           // 4 gathers in flight
            int s0 = csr_s[e], s1 = csr_s[e + 1], s2 = csr_s[e + 2], s3 = csr_s[e + 3];
            float w0 = vbuf[e * NH1 + q], w1 = vbuf[(e + 1) * NH1 + q];
            float w2 = vbuf[(e + 2) * NH1 + q], w3 = vbuf[(e + 3) * NH1 + q];
            acc = fmaf(w0, h1pre[s0 * D1 + t], acc);
            acc = fmaf(w1, h1pre[s1 * D1 + t], acc);
            acc = fmaf(w2, h1pre[s2 * D1 + t], acc);
            acc = fmaf(w3, h1pre[s3 * D1 + t], acc);
        }
        for (; e < deg; ++e)
            acc = fmaf(vbuf[e * NH1 + q], h1pre[csr_s[e] * D1 + t], acc);
        val = acc / dq + b1[t];
    } else {
        // fallback: recompute path (uniform branch, rare)
        int h = t & 7;
        float aldh = ald1[n * NH1 + h];
        float m = -3.4e38f;
        for (int i = beg + (t >> 3); i < end; i += 8) {
            int s = csr[i];
            float v = als1[s * NH1 + h] + aldh;
            v = v > 0.f ? v : NEG_SLOPE * v;
            m = fmaxf(m, v);
        }
        m = fmaxf(m, __shfl_xor(m, 8));
        m = fmaxf(m, __shfl_xor(m, 16));
        m = fmaxf(m, __shfl_xor(m, 32));
        float den = 0.f;
        for (int i = beg + (t >> 3); i < end; i += 8) {
            int s = csr[i];
            float v = als1[s * NH1 + h] + aldh;
            v = v > 0.f ? v : NEG_SLOPE * v;
            den += expf(v - m);
        }
        den += __shfl_xor(den, 8);
        den += __shfl_xor(den, 16);
        den += __shfl_xor(den, 32);
        int q = t >> 3;
        float mq = __shfl(m, q);
        float dq = __shfl(den, q);
        float aldq = ald1[n * NH1 + q];
        float acc = 0.f;
        for (int i = beg; i < end; ++i) {
            int s = csr[i];
            float v = als1[s * NH1 + q] + aldq;
            v = v > 0.f ? v : NEG_SLOPE * v;
            acc = fmaf(expf(v - mq), h1pre[s * D1 + t], acc);
        }
        val = acc / dq + b1[t];
    }
    val = val > 0.f ? val : expm1f(val);         // ELU -> out1[n][t] in-register
    // ---- fused gemm2 + logits2: h2[c] = sum_t out1[t]*W2[t][c] ----
    __syncthreads();
    vals[t] = val;
    __syncthreads();
    int g = t >> 4, c = t & 15;                  // 4 k-groups x 16 channels
    float a2 = 0.f;
    const float* w2p = W2 + g * 16 * NC + c;
#pragma unroll
    for (int j = 0; j < 16; ++j)
        a2 = fmaf(vals[g * 16 + j], w2p[j * NC], a2);
    a2 += __shfl_xor(a2, 16);
    a2 += __shfl_xor(a2, 32);                    // all lanes: h2pre[n][c], c=t&15
    if (t < 16) h2pre[(size_t)n * NC + t] = a2;
    float ps = a2 * a_src2[c], pd = a2 * a_dst2[c];
#pragma unroll
    for (int d = 1; d < 16; d <<= 1) {
        ps += __shfl_xor(ps, d);
        pd += __shfl_xor(pd, d);
    }
    if (t == 0) { als2[n] = ps; ald2[n] = pd; }
}

// ------- Layer-2 softmax + agg + bias + fused log_softmax, one wave/node -------
__global__ __launch_bounds__(64) void agg2_k(const float* __restrict__ h2pre,
                                             const float* __restrict__ als2, const float* __restrict__ ald2,
                                             const int* __restrict__ offsets, const int* __restrict__ csr,
                                             const float* __restrict__ b2,
                                             float* __restrict__ z, float* __restrict__ out_ls) {
    __shared__ int   csr2[CAP];
    __shared__ float wb2[CAP];
    int n = blockIdx.x, t = threadIdx.x;
    int beg = offsets[n], end = offsets[n + 1];
    int deg = end - beg;
    float aldn = ald2[n];
    int eg = t >> 4, c = t & 15;                 // 4 edge-groups x 16 channels
    float zv;
    if (deg <= CAP) {
        float m = -3.4e38f;
        for (int i = t; i < deg; i += 64) {
            int s = csr[beg + i];
            csr2[i] = s;
            float v = als2[s] + aldn;
            v = v > 0.f ? v : NEG_SLOPE * v;
            wb2[i] = v;
            m = fmaxf(m, v);
        }
#pragma unroll
        for (int d = 1; d < 64; d <<= 1) m = fmaxf(m, __shfl_xor(m, d));
        float den = 0.f;
        for (int i = t; i < deg; i += 64) {
            float w = expf(wb2[i] - m);
            wb2[i] = w;
            den += w;
        }
#pragma unroll
        for (int d = 1; d < 64; d <<= 1) den += __shfl_xor(den, d);
        __syncthreads();
        float acc = 0.f;
        int e = eg;
        for (; e + 4 < deg; e += 8) {            // 2 gathers in flight per group
            int s0 = csr2[e], s1 = csr2[e + 4];
            float w0 = wb2[e], w1 = wb2[e + 4];
            acc = fmaf(w0, h2pre[s0 * NC + c], acc);
            acc = fmaf(w1, h2pre[s1 * NC + c], acc);
        }
        for (; e < deg; e += 4)
            acc = fmaf(wb2[e], h2pre[csr2[e] * NC + c], acc);
        acc += __shfl_xor(acc, 16);
        acc += __shfl_xor(acc, 32);
        zv = acc / den + b2[c];
    } else {
        float m = -3.4e38f;
        for (int i = beg + t; i < end; i += 64) {
            float v = als2[csr[i]] + aldn;
            v = v > 0.f ? v : NEG_SLOPE * v;
            m = fmaxf(m, v);
        }
#pragma unroll
        for (int d = 1; d < 64; d <<= 1) m = fmaxf(m, __shfl_xor(m, d));
        float den = 0.f;
        for (int i = beg + t; i < end; i += 64) {
            float v = als2[csr[i]] + aldn;
            v = v > 0.f ? v : NEG_SLOPE * v;
            den += expf(v - m);
        }
#pragma unroll
        for (int d = 1; d < 64; d <<= 1) den += __shfl_xor(den, d);
        float acc = 0.f;
        for (int i = beg + eg; i < end; i += 4) {
            int s = csr[i];
            float v = als2[s] + aldn;
            v = v > 0.f ? v : NEG_SLOPE * v;
            acc = fmaf(expf(v - m), h2pre[(size_t)s * NC + c], acc);
        }
        acc += __shfl_xor(acc, 16);
        acc += __shfl_xor(acc, 32);
        zv = acc / den + b2[c];
    }
    if (t < 16) z[(size_t)n * NC + t] = zv;
    // log_softmax over the 16 channels (xor 1,2,4,8 stays within 16-lane groups)
    float zm = zv;
#pragma unroll
    for (int d = 1; d < 16; d <<= 1) zm = fmaxf(zm, __shfl_xor(zm, d));
    float se = expf(zv - zm);
#pragma unroll
    for (int d = 1; d < 16; d <<= 1) se += __shfl_xor(se, d);
    if (t < 16) out_ls[(size_t)n * NC + t] = zv - (zm + logf(se));
}

// ---------------- Gram: out[8192,8192] = z @ z^T ----------------
__global__ __launch_bounds__(256) void gram_k(const float* __restrict__ z,
                                              float* __restrict__ out) {
    __shared__ __align__(16) float rz[64 * 16];   // 64 row vectors
    int tid = threadIdx.x;
    int colBase = blockIdx.x * 256;
    int rowBase = blockIdx.y * 64;
    ((float4*)rz)[tid] = ((const float4*)z)[rowBase * 4 + tid];
    int j = colBase + tid;
    float c[16];
#pragma unroll
    for (int k4 = 0; k4 < 4; ++k4) {
        float4 v = ((const float4*)(z + (size_t)j * 16))[k4];
        c[k4 * 4 + 0] = v.x; c[k4 * 4 + 1] = v.y; c[k4 * 4 + 2] = v.z; c[k4 * 4 + 3] = v.w;
    }
    __syncthreads();
#pragma unroll 4
    for (int r = 0; r < 64; ++r) {
        const float* zr = &rz[r * 16];
        float acc = 0.f;
#pragma unroll
        for (int k = 0; k < 16; ++k) acc = fmaf(c[k], zr[k], acc);
        out[(size_t)(rowBase + r) * N_NODES + j] = acc;
    }
}

extern "C" void kernel_launch(void* const* d_in, const int* in_sizes, int n_in,
                              void* d_out, int out_size, void* d_ws, size_t ws_size,
                              hipStream_t stream) {
    (void)in_sizes; (void)n_in; (void)out_size; (void)ws_size;
    const float* x      = (const float*)d_in[0];
    const int*   ei     = (const int*)d_in[1];
    const float* W1     = (const float*)d_in[2];
    const float* a_src1 = (const float*)d_in[3];
    const float* a_dst1 = (const float*)d_in[4];
    const float* b1     = (const float*)d_in[5];
    const float* W2     = (const float*)d_in[6];
    const float* a_src2 = (const float*)d_in[7];
    const float* a_dst2 = (const float*)d_in[8];
    const float* b2     = (const float*)d_in[9];
    float* out = (float*)d_out;

    char* ws = (char*)d_ws;                    // all offsets 256B-aligned
    float* h1pre  = (float*)(ws + 0);          // 2 MB
    float* als1   = (float*)(ws + 4194304);    // 256 KB
    float* ald1   = (float*)(ws + 4456448);    // 256 KB
    float* h2pre  = (float*)(ws + 4718592);    // 512 KB
    float* als2   = (float*)(ws + 5242880);    // 32 KB
    float* ald2   = (float*)(ws + 5275648);    // 32 KB
    float* zarr   = (float*)(ws + 5308416);    // 512 KB
    int*   counts = (int*)  (ws + 5832704);    // 32 KB
    int*   offsets= (int*)  (ws + 5865472);    // 8193 ints
    int*   cursor = (int*)  (ws + 5898496);    // 32 KB
    int*   csr    = (int*)  (ws + 5931264);    // 1.03 MB

    // gemm1 also zeroes counts (it fully precedes the CSR kernel in stream order)
    gemm1_k<<<N_NODES / 32, 256, 0, stream>>>(x, W1, a_src1, a_dst1, h1pre, als1, ald1, counts);

    {
        void* cargs[] = {(void*)&ei, (void*)&counts, (void*)&offsets, (void*)&cursor, (void*)&csr};
        hipLaunchCooperativeKernel((const void*)csr_coop_k, dim3(256), dim3(1024), cargs, 0, stream);
    }

    agg1_k<<<N_NODES, 64, 0, stream>>>(h1pre, als1, ald1, offsets, csr, b1,
                                       W2, a_src2, a_dst2, h2pre, als2, ald2);
    agg2_k<<<N_NODES, 64, 0, stream>>>(h2pre, als2, ald2, offsets, csr, b2, zarr, out);

    gram_k<<<dim3(N_NODES / 256, N_NODES / 64), 256, 0, stream>>>(zarr, out + (size_t)N_NODES * NC);
}

// Round 3
// 347.121 us; speedup vs baseline: 1.5901x; 1.5901x over previous
//
#include <hip/hip_runtime.h>
#include <math.h>

#define N_NODES 8192
#define F_IN 512
#define NH1 8
#define C1 8
#define D1 64   // NH1*C1
#define NC 16
#define E_EDGES 262144
#define TOT_EDGES (E_EDGES + N_NODES)
#define NEG_SLOPE 0.2f
#define CAP 128     // fast-path degree cap (max observed degree ~65 incl self-loop)
#define CAPE 128    // ELL row stride
#define OVF_MAX 8192

// ---- GEMM1 + fused logits1 (+ counts zeroing): h1pre[N,64] = x @ W1 ----------
// BM=32 -> 256 blocks. Thread tile 2x4. Zeroes counts[8193] (stream-ordered
// before ell_k, so no separate memset dispatch).
__global__ __launch_bounds__(256) void gemm1_k(const float* __restrict__ x,
                                               const float* __restrict__ W1,
                                               const float* __restrict__ a_src1,
                                               const float* __restrict__ a_dst1,
                                               float* __restrict__ h1pre,
                                               float* __restrict__ als1,
                                               float* __restrict__ ald1,
                                               int* __restrict__ counts) {
    __shared__ __align__(16) float As[32 * 34];  // [k=32][m=32 +2 pad]
    __shared__ __align__(16) float Bs[32 * 68];  // [k=32][n=64 +4 pad]
    int tid = threadIdx.x;
    if (tid < 32) counts[blockIdx.x * 32 + tid] = 0;
    if (blockIdx.x == 0 && tid == 32) counts[N_NODES] = 0;   // overflow counter
    int rowBase = blockIdx.x * 32;
    int rm = tid >> 4, rn = tid & 15;            // rows rm*2.., cols rn*4..
    float acc[2][4] = {};
    for (int k0 = 0; k0 < F_IN; k0 += 32) {
#pragma unroll
        for (int j = 0; j < 4; ++j) {            // A tile: 32 rows x 32 k
            int i = tid + 256 * j;
            int r = i >> 5, c = i & 31;
            As[c * 34 + r] = x[(rowBase + r) * F_IN + k0 + c];
        }
#pragma unroll
        for (int j = 0; j < 8; ++j) {            // B tile: 32 k x 64 cols
            int i = tid + 256 * j;
            int rr = i >> 6, cc = i & 63;
            Bs[rr * 68 + cc] = W1[(k0 + rr) * D1 + cc];
        }
        __syncthreads();
#pragma unroll
        for (int kk = 0; kk < 32; ++kk) {
            float2 a = *(const float2*)&As[kk * 34 + rm * 2];
            float4 b = *(const float4*)&Bs[kk * 68 + rn * 4];
            float av[2] = {a.x, a.y};
            float bv[4] = {b.x, b.y, b.z, b.w};
#pragma unroll
            for (int jj = 0; jj < 2; ++jj)
#pragma unroll
                for (int ll = 0; ll < 4; ++ll)
                    acc[jj][ll] = fmaf(av[jj], bv[ll], acc[jj][ll]);
        }
        __syncthreads();
    }
    int h = rn >> 1, half = rn & 1;
#pragma unroll
    for (int jj = 0; jj < 2; ++jj) {
        int row = rowBase + rm * 2 + jj;
        float4 o = {acc[jj][0], acc[jj][1], acc[jj][2], acc[jj][3]};
        *(float4*)&h1pre[(size_t)row * D1 + rn * 4] = o;
        float ps = 0.f, pd = 0.f;
#pragma unroll
        for (int ll = 0; ll < 4; ++ll) {
            ps = fmaf(acc[jj][ll], a_src1[h * C1 + half * 4 + ll], ps);
            pd = fmaf(acc[jj][ll], a_dst1[h * C1 + half * 4 + ll], pd);
        }
        ps += __shfl_xor(ps, 1);
        pd += __shfl_xor(pd, 1);
        if (half == 0) {
            als1[row * NH1 + h] = ps;
            ald1[row * NH1 + h] = pd;
        }
    }
}

// ------- ELL build: one pass, no scan/scatter. counts[dst] ends as degree. -------
__global__ void ell_k(const int* __restrict__ ei, int* __restrict__ counts,
                      int* __restrict__ ell, int* __restrict__ ovfd, int* __restrict__ ovfs) {
    int i = blockIdx.x * blockDim.x + threadIdx.x;
    if (i >= TOT_EDGES) return;
    int src, dst;
    if (i < E_EDGES) { src = ei[i]; dst = ei[E_EDGES + i]; }
    else             { src = i - E_EDGES; dst = src; }
    int pos = atomicAdd(&counts[dst], 1);
    if (pos < CAPE) {
        ell[dst * CAPE + pos] = src;
    } else {                                     // never for this input; correctness only
        int p2 = atomicAdd(&counts[N_NODES], 1);
        if (p2 < OVF_MAX) { ovfd[p2] = dst; ovfs[p2] = src; }
    }
}

// -- Layer-1 softmax+agg, fused ELU + gemm2 + logits2; one wave per dst node --
__global__ __launch_bounds__(64) void agg1_k(const float* __restrict__ h1pre,
                                             const float* __restrict__ als1, const float* __restrict__ ald1,
                                             const int* __restrict__ counts, const int* __restrict__ ell,
                                             const int* __restrict__ ovfd, const int* __restrict__ ovfs,
                                             const float* __restrict__ b1,
                                             const float* __restrict__ W2,
                                             const float* __restrict__ a_src2, const float* __restrict__ a_dst2,
                                             float* __restrict__ h2pre,
                                             float* __restrict__ als2, float* __restrict__ ald2) {
    __shared__ int   csr_s[CAP];
    __shared__ float vbuf[CAP * NH1];
    __shared__ float vals[64];
    int n = blockIdx.x, t = threadIdx.x;
    int deg = counts[n];
    int beg = n * CAPE;
    float val;
    if (deg <= CAP) {
        for (int i = t; i < deg; i += 64) csr_s[i] = ell[beg + i];
        __syncthreads();
        int h = t & 7, eo = t >> 3;              // 8 edges in flight x 8 heads
        float aldh = ald1[n * NH1 + h];
        float m = -3.4e38f;
        for (int e = eo; e < deg; e += 8) {
            int s = csr_s[e];
            float v = als1[s * NH1 + h] + aldh;
            v = v > 0.f ? v : NEG_SLOPE * v;
            vbuf[e * NH1 + h] = v;
            m = fmaxf(m, v);
        }
        m = fmaxf(m, __shfl_xor(m, 8));
        m = fmaxf(m, __shfl_xor(m, 16));
        m = fmaxf(m, __shfl_xor(m, 32));
        float den = 0.f;
        for (int e = eo; e < deg; e += 8) {
            float w = expf(vbuf[e * NH1 + h] - m);
            vbuf[e * NH1 + h] = w;
            den += w;
        }
        den += __shfl_xor(den, 8);
        den += __shfl_xor(den, 16);
        den += __shfl_xor(den, 32);
        __syncthreads();
        int q = t >> 3;
        float dq = __shfl(den, q);
        float acc = 0.f;
        int e = 0;
        for (; e + 4 <= deg; e += 4) {           // 4 gathers in flight
            int s0 = csr_s[e], s1 = csr_s[e + 1], s2 = csr_s[e + 2], s3 = csr_s[e + 3];
            float w0 = vbuf[e * NH1 + q], w1 = vbuf[(e + 1) * NH1 + q];
            float w2 = vbuf[(e + 2) * NH1 + q], w3 = vbuf[(e + 3) * NH1 + q];
            acc = fmaf(w0, h1pre[s0 * D1 + t], acc);
            acc = fmaf(w1, h1pre[s1 * D1 + t], acc);
            acc = fmaf(w2, h1pre[s2 * D1 + t], acc);
            acc = fmaf(w3, h1pre[s3 * D1 + t], acc);
        }
        for (; e < deg; ++e)
            acc = fmaf(vbuf[e * NH1 + q], h1pre[csr_s[e] * D1 + t], acc);
        val = acc / dq + b1[t];
    } else {
        // slow path: deg > CAP (never for this input; correctness only)
        int degc = deg < CAPE ? deg : CAPE;
        int novf = counts[N_NODES]; novf = novf < OVF_MAX ? novf : OVF_MAX;
        int h = t & 7;
        float aldh = ald1[n * NH1 + h];
        float m = -3.4e38f;
        for (int i = (t >> 3); i < degc; i += 8) {
            int s = ell[beg + i];
            float v = als1[s * NH1 + h] + aldh;
            v = v > 0.f ? v : NEG_SLOPE * v;
            m = fmaxf(m, v);
        }
        for (int k = (t >> 3); k < novf; k += 8) if (ovfd[k] == n) {
            int s = ovfs[k];
            float v = als1[s * NH1 + h] + aldh;
            v = v > 0.f ? v : NEG_SLOPE * v;
            m = fmaxf(m, v);
        }
        m = fmaxf(m, __shfl_xor(m, 8));
        m = fmaxf(m, __shfl_xor(m, 16));
        m = fmaxf(m, __shfl_xor(m, 32));
        float den = 0.f;
        for (int i = (t >> 3); i < degc; i += 8) {
            int s = ell[beg + i];
            float v = als1[s * NH1 + h] + aldh;
            v = v > 0.f ? v : NEG_SLOPE * v;
            den += expf(v - m);
        }
        for (int k = (t >> 3); k < novf; k += 8) if (ovfd[k] == n) {
            int s = ovfs[k];
            float v = als1[s * NH1 + h] + aldh;
            v = v > 0.f ? v : NEG_SLOPE * v;
            den += expf(v - m);
        }
        den += __shfl_xor(den, 8);
        den += __shfl_xor(den, 16);
        den += __shfl_xor(den, 32);
        int q = t >> 3;
        float mq = __shfl(m, q);
        float dq = __shfl(den, q);
        float aldq = ald1[n * NH1 + q];
        float acc = 0.f;
        for (int i = 0; i < degc; ++i) {
            int s = ell[beg + i];
            float v = als1[s * NH1 + q] + aldq;
            v = v > 0.f ? v : NEG_SLOPE * v;
            acc = fmaf(expf(v - mq), h1pre[s * D1 + t], acc);
        }
        for (int k = 0; k < novf; ++k) if (ovfd[k] == n) {
            int s = ovfs[k];
            float v = als1[s * NH1 + q] + aldq;
            v = v > 0.f ? v : NEG_SLOPE * v;
            acc = fmaf(expf(v - mq), h1pre[s * D1 + t], acc);
        }
        val = acc / dq + b1[t];
    }
    val = val > 0.f ? val : expm1f(val);         // ELU -> out1[n][t] in-register
    // ---- fused gemm2 + logits2 ----
    __syncthreads();
    vals[t] = val;
    __syncthreads();
    int g = t >> 4, c = t & 15;                  // 4 k-groups x 16 channels
    float a2 = 0.f;
    const float* w2p = W2 + g * 16 * NC + c;
#pragma unroll
    for (int j = 0; j < 16; ++j)
        a2 = fmaf(vals[g * 16 + j], w2p[j * NC], a2);
    a2 += __shfl_xor(a2, 16);
    a2 += __shfl_xor(a2, 32);
    if (t < 16) h2pre[(size_t)n * NC + t] = a2;
    float ps = a2 * a_src2[c], pd = a2 * a_dst2[c];
#pragma unroll
    for (int d = 1; d < 16; d <<= 1) {
        ps += __shfl_xor(ps, d);
        pd += __shfl_xor(pd, d);
    }
    if (t == 0) { als2[n] = ps; ald2[n] = pd; }
}

// ------- Layer-2 softmax + agg + bias + fused log_softmax, one wave/node -------
__global__ __launch_bounds__(64) void agg2_k(const float* __restrict__ h2pre,
                                             const float* __restrict__ als2, const float* __restrict__ ald2,
                                             const int* __restrict__ counts, const int* __restrict__ ell,
                                             const int* __restrict__ ovfd, const int* __restrict__ ovfs,
                                             const float* __restrict__ b2,
                                             float* __restrict__ z, float* __restrict__ out_ls) {
    __shared__ int   csr2[CAP];
    __shared__ float wb2[CAP];
    int n = blockIdx.x, t = threadIdx.x;
    int deg = counts[n];
    int beg = n * CAPE;
    float aldn = ald2[n];
    int eg = t >> 4, c = t & 15;                 // 4 edge-groups x 16 channels
    float zv;
    if (deg <= CAP) {
        float m = -3.4e38f;
        for (int i = t; i < deg; i += 64) {
            int s = ell[beg + i];
            csr2[i] = s;
            float v = als2[s] + aldn;
            v = v > 0.f ? v : NEG_SLOPE * v;
            wb2[i] = v;
            m = fmaxf(m, v);
        }
#pragma unroll
        for (int d = 1; d < 64; d <<= 1) m = fmaxf(m, __shfl_xor(m, d));
        float den = 0.f;
        for (int i = t; i < deg; i += 64) {
            float w = expf(wb2[i] - m);
            wb2[i] = w;
            den += w;
        }
#pragma unroll
        for (int d = 1; d < 64; d <<= 1) den += __shfl_xor(den, d);
        __syncthreads();
        float acc = 0.f;
        int e = eg;
        for (; e + 4 < deg; e += 8) {            // 2 gathers in flight per group
            int s0 = csr2[e], s1 = csr2[e + 4];
            float w0 = wb2[e], w1 = wb2[e + 4];
            acc = fmaf(w0, h2pre[s0 * NC + c], acc);
            acc = fmaf(w1, h2pre[s1 * NC + c], acc);
        }
        for (; e < deg; e += 4)
            acc = fmaf(wb2[e], h2pre[csr2[e] * NC + c], acc);
        acc += __shfl_xor(acc, 16);
        acc += __shfl_xor(acc, 32);
        zv = acc / den + b2[c];
    } else {
        // slow path (never for this input)
        int degc = deg < CAPE ? deg : CAPE;
        int novf = counts[N_NODES]; novf = novf < OVF_MAX ? novf : OVF_MAX;
        float m = -3.4e38f;
        for (int i = t; i < degc; i += 64) {
            float v = als2[ell[beg + i]] + aldn;
            v = v > 0.f ? v : NEG_SLOPE * v;
            m = fmaxf(m, v);
        }
        for (int k = t; k < novf; k += 64) if (ovfd[k] == n) {
            float v = als2[ovfs[k]] + aldn;
            v = v > 0.f ? v : NEG_SLOPE * v;
            m = fmaxf(m, v);
        }
#pragma unroll
        for (int d = 1; d < 64; d <<= 1) m = fmaxf(m, __shfl_xor(m, d));
        float den = 0.f;
        for (int i = t; i < degc; i += 64) {
            float v = als2[ell[beg + i]] + aldn;
            v = v > 0.f ? v : NEG_SLOPE * v;
            den += expf(v - m);
        }
        for (int k = t; k < novf; k += 64) if (ovfd[k] == n) {
            float v = als2[ovfs[k]] + aldn;
            v = v > 0.f ? v : NEG_SLOPE * v;
            den += expf(v - m);
        }
#pragma unroll
        for (int d = 1; d < 64; d <<= 1) den += __shfl_xor(den, d);
        float acc = 0.f;
        for (int i = eg; i < degc; i += 4) {
            int s = ell[beg + i];
            float v = als2[s] + aldn;
            v = v > 0.f ? v : NEG_SLOPE * v;
            acc = fmaf(expf(v - m), h2pre[(size_t)s * NC + c], acc);
        }
        for (int k = eg; k < novf; k += 4) if (ovfd[k] == n) {
            int s = ovfs[k];
            float v = als2[s] + aldn;
            v = v > 0.f ? v : NEG_SLOPE * v;
            acc = fmaf(expf(v - m), h2pre[(size_t)s * NC + c], acc);
        }
        acc += __shfl_xor(acc, 16);
        acc += __shfl_xor(acc, 32);
        zv = acc / den + b2[c];
    }
    if (t < 16) z[(size_t)n * NC + t] = zv;
    float zm = zv;
#pragma unroll
    for (int d = 1; d < 16; d <<= 1) zm = fmaxf(zm, __shfl_xor(zm, d));
    float se = expf(zv - zm);
#pragma unroll
    for (int d = 1; d < 16; d <<= 1) se += __shfl_xor(se, d);
    if (t < 16) out_ls[(size_t)n * NC + t] = zv - (zm + logf(se));
}

// ---------------- Gram: out[8192,8192] = z @ z^T ----------------
__global__ __launch_bounds__(256) void gram_k(const float* __restrict__ z,
                                              float* __restrict__ out) {
    __shared__ __align__(16) float rz[64 * 16];   // 64 row vectors
    int tid = threadIdx.x;
    int colBase = blockIdx.x * 256;
    int rowBase = blockIdx.y * 64;
    ((float4*)rz)[tid] = ((const float4*)z)[rowBase * 4 + tid];
    int j = colBase + tid;
    float c[16];
#pragma unroll
    for (int k4 = 0; k4 < 4; ++k4) {
        float4 v = ((const float4*)(z + (size_t)j * 16))[k4];
        c[k4 * 4 + 0] = v.x; c[k4 * 4 + 1] = v.y; c[k4 * 4 + 2] = v.z; c[k4 * 4 + 3] = v.w;
    }
    __syncthreads();
#pragma unroll 4
    for (int r = 0; r < 64; ++r) {
        const float* zr = &rz[r * 16];
        float acc = 0.f;
#pragma unroll
        for (int k = 0; k < 16; ++k) acc = fmaf(c[k], zr[k], acc);
        out[(size_t)(rowBase + r) * N_NODES + j] = acc;
    }
}

extern "C" void kernel_launch(void* const* d_in, const int* in_sizes, int n_in,
                              void* d_out, int out_size, void* d_ws, size_t ws_size,
                              hipStream_t stream) {
    (void)in_sizes; (void)n_in; (void)out_size; (void)ws_size;
    const float* x      = (const float*)d_in[0];
    const int*   ei     = (const int*)d_in[1];
    const float* W1     = (const float*)d_in[2];
    const float* a_src1 = (const float*)d_in[3];
    const float* a_dst1 = (const float*)d_in[4];
    const float* b1     = (const float*)d_in[5];
    const float* W2     = (const float*)d_in[6];
    const float* a_src2 = (const float*)d_in[7];
    const float* a_dst2 = (const float*)d_in[8];
    const float* b2     = (const float*)d_in[9];
    float* out = (float*)d_out;

    char* ws = (char*)d_ws;                    // all offsets 256B-aligned
    float* h1pre  = (float*)(ws + 0);          // 2 MB
    float* als1   = (float*)(ws + 2097152);    // 256 KB
    float* ald1   = (float*)(ws + 2359296);    // 256 KB
    float* h2pre  = (float*)(ws + 2621440);    // 512 KB
    float* als2   = (float*)(ws + 3145728);    // 32 KB
    float* ald2   = (float*)(ws + 3178496);    // 32 KB
    float* zarr   = (float*)(ws + 3211264);    // 512 KB
    int*   counts = (int*)  (ws + 3735552);    // 8193 ints (pad to 33 KB)
    int*   ell    = (int*)  (ws + 3768576);    // 8192*128*4 = 4 MB
    int*   ovfd   = (int*)  (ws + 7962880);    // 32 KB
    int*   ovfs   = (int*)  (ws + 7995648);    // 32 KB  (end ~8.03 MB)

    // gemm1 also zeroes counts+ovf counter (stream-ordered before ell_k)
    gemm1_k<<<N_NODES / 32, 256, 0, stream>>>(x, W1, a_src1, a_dst1, h1pre, als1, ald1, counts);
    ell_k<<<(TOT_EDGES + 255) / 256, 256, 0, stream>>>(ei, counts, ell, ovfd, ovfs);
    agg1_k<<<N_NODES, 64, 0, stream>>>(h1pre, als1, ald1, counts, ell, ovfd, ovfs, b1,
                                       W2, a_src2, a_dst2, h2pre, als2, ald2);
    agg2_k<<<N_NODES, 64, 0, stream>>>(h2pre, als2, ald2, counts, ell, ovfd, ovfs, b2, zarr, out);
    gram_k<<<dim3(N_NODES / 256, N_NODES / 64), 256, 0, stream>>>(zarr, out + (size_t)N_NODES * NC);
}